// Round 6
// baseline (236.764 us; speedup 1.0000x reference)
//
#include <hip/hip_runtime.h>

// Problem constants (from reference)
#define VOCAB 50257
#define SEQ   2048
#define EMB   512
#define BATCH 8
#define NTOK  (BATCH * SEQ)   // 16384

#define LISTCAP 4096          // positions per 64-wide v-tile (mean ~21, Poisson)

// ---------------------------------------------------------------------------
// Single fused kernel. Grid: (786 v-tiles, 2 e-halves), 256 threads.
// Each block:
//   1) scans all 16K tokens (L2-resident) and compacts positions whose token
//      lies in [v0, v0+64) into an LDS list (packed ts | v_l<<14).
//   2) for each of 4 e-chunks: stage a 64x64 W_emb tile in LDS (coalesced
//      256 B row reads, nontemporal — every W_emb line is read exactly once
//      device-wide), then for each listed position write the 256 B output
//      segment out[ts*EMB + e0c .. +64) = column(v_l) + W_pos row segment.
// LDS aliasing is 2-way on both tile phases (free on gfx950).
// Traffic: 103 MB R (W_emb) + 33.5 MB W (out) + ~5 MB (tokens/W_pos) ~= 141 MB.
// ---------------------------------------------------------------------------
__global__ __launch_bounds__(256)
void fused_emb_k(const int* __restrict__ tokens,
                 const float* __restrict__ W_emb,   // (EMB, VOCAB)
                 const float* __restrict__ W_pos,   // (SEQ, EMB)
                 float* __restrict__ out) {         // (NTOK, EMB)
    __shared__ float tile[64][65];
    __shared__ int list[LISTCAP];
    __shared__ int cnt;

    const int tid  = threadIdx.x;
    const int lane = tid & 63;
    const int wv   = tid >> 6;          // wave 0..3
    const int v0   = blockIdx.x * 64;
    const int e0   = blockIdx.y * 256;  // e-half origin

    if (tid == 0) cnt = 0;
    __syncthreads();

    // 1) compact positions of tokens in this v-tile (coalesced 256 B reads/iter)
    for (int ts = tid; ts < NTOK; ts += 256) {
        const int d = tokens[ts] - v0;
        if ((unsigned)d < 64u) {
            const int p = atomicAdd(&cnt, 1);
            if (p < LISTCAP) list[p] = ts | (d << 14);
        }
    }
    __syncthreads();
    const int n = min(cnt, LISTCAP);

    // 2) e-chunks of 64 rows
    for (int ec = 0; ec < 4; ++ec) {
        const int e0c = e0 + ec * 64;
        const int v   = v0 + lane;
#pragma unroll
        for (int j = 0; j < 16; ++j) {
            const int e_l = wv * 16 + j;
            tile[e_l][lane] = (v < VOCAB)
                ? __builtin_nontemporal_load(&W_emb[(size_t)(e0c + e_l) * VOCAB + v])
                : 0.0f;
        }
        __syncthreads();

        for (int p = wv; p < n; p += 4) {
            const int pk  = list[p];
            const int ts  = pk & (NTOK - 1);
            const int v_l = pk >> 14;
            const int s   = ts & (SEQ - 1);
            const float val = tile[lane][v_l]
                            + W_pos[(size_t)s * EMB + e0c + lane];
            __builtin_nontemporal_store(val, &out[(size_t)ts * EMB + e0c + lane]);
        }
        __syncthreads();
    }
}

extern "C" void kernel_launch(void* const* d_in, const int* in_sizes, int n_in,
                              void* d_out, int out_size, void* d_ws, size_t ws_size,
                              hipStream_t stream) {
    const int*   tokens = (const int*)d_in[0];
    const float* W_emb  = (const float*)d_in[1];   // (EMB, VOCAB)
    const float* W_pos  = (const float*)d_in[2];   // (SEQ, EMB)
    float*       out    = (float*)d_out;           // (BATCH*SEQ, EMB)

    dim3 grid((VOCAB + 63) / 64, EMB / 256);       // 786 x 2
    fused_emb_k<<<grid, 256, 0, stream>>>(tokens, W_emb, W_pos, out);
}

// Round 7
// 186.047 us; speedup vs baseline: 1.2726x; 1.2726x over previous
//
#include <hip/hip_runtime.h>

// Problem constants (from reference)
#define VOCAB 50257
#define SEQ   2048
#define EMB   512
#define BATCH 8
#define NTOK  (BATCH * SEQ)          // 16384
#define NBINS ((VOCAB + 63) / 64)    // 786 vocab bins of width 64

typedef float floatx4 __attribute__((ext_vector_type(4)));

// ---------------------------------------------------------------------------
// Workspace layout (ints): counts[1024] | offs[1024] | cursor[1024] | ents[NTOK]
// CSR inverted index: for each 64-wide vocab bin, the list of token positions,
// entry = ts | (v_local << 14)  (ts < 2^14, v_local < 64).
// ---------------------------------------------------------------------------
#define WS_COUNTS 0
#define WS_OFFS   1024
#define WS_CURSOR 2048
#define WS_ENTS   3072
#define WS_NEED_BYTES ((WS_ENTS + NTOK) * sizeof(int))

__global__ __launch_bounds__(256)
void init_k(int* __restrict__ ws) {
    const int i = blockIdx.x * 256 + threadIdx.x;
    if (i < 1024) ws[WS_COUNTS + i] = 0;
}

__global__ __launch_bounds__(256)
void count_k(const int* __restrict__ tokens, int* __restrict__ ws) {
    const int i = blockIdx.x * 256 + threadIdx.x;
    if (i < NTOK) atomicAdd(&ws[WS_COUNTS + (tokens[i] >> 6)], 1);
}

// Single-block exclusive scan of the 786 bin counts -> offs, cursor.
__global__ __launch_bounds__(256)
void scan_k(int* __restrict__ ws) {
    __shared__ int part[256];
    const int t = threadIdx.x;
    int local[4];
    int s = 0;
#pragma unroll
    for (int j = 0; j < 4; ++j) {
        const int i = t * 4 + j;
        local[j] = s;
        s += (i < NBINS) ? ws[WS_COUNTS + i] : 0;
    }
    part[t] = s;
    __syncthreads();
    int v = s;
    for (int d = 1; d < 256; d <<= 1) {
        const int add = (t >= d) ? part[t - d] : 0;
        __syncthreads();
        v += add;
        part[t] = v;
        __syncthreads();
    }
    const int base = v - s;   // exclusive prefix of this thread's 4-bin chunk
#pragma unroll
    for (int j = 0; j < 4; ++j) {
        const int i = t * 4 + j;
        if (i < NBINS) {
            const int o = base + local[j];
            ws[WS_OFFS + i]   = o;
            ws[WS_CURSOR + i] = o;
        }
    }
    if (t == 255) ws[WS_OFFS + NBINS] = v;   // == NTOK
}

__global__ __launch_bounds__(256)
void fill_k(const int* __restrict__ tokens, int* __restrict__ ws) {
    const int i = blockIdx.x * 256 + threadIdx.x;
    if (i < NTOK) {
        const int t = tokens[i];
        const int slot = atomicAdd(&ws[WS_CURSOR + (t >> 6)], 1);
        ws[WS_ENTS + slot] = i | ((t & 63) << 14);
    }
}

// ---------------------------------------------------------------------------
// Fused embedding kernel. Grid (786 bins, 8 e-chunks), 256 threads.
// Stage 64x64 W_emb tile (coalesced 256 B row reads, each line read once
// device-wide), then for each CSR position write the fused 256 B output
// segment. LDS aliasing 2-way on both phases (free). No token scan.
// ---------------------------------------------------------------------------
__global__ __launch_bounds__(256)
void fused_emb_k(const float* __restrict__ W_emb,   // (EMB, VOCAB)
                 const float* __restrict__ W_pos,   // (SEQ, EMB)
                 const int* __restrict__ ws,
                 float* __restrict__ out) {         // (NTOK, EMB)
    __shared__ float tile[64][65];
    const int tid  = threadIdx.x;
    const int lane = tid & 63;
    const int wv   = tid >> 6;          // wave 0..3
    const int b    = blockIdx.x;        // vocab bin
    const int e0c  = blockIdx.y * 64;   // e-chunk origin
    const int beg  = ws[WS_OFFS + b];
    const int end  = ws[WS_OFFS + b + 1];
    if (beg == end) return;             // bin unused: skip its W_emb columns

    const int v = b * 64 + lane;
    if (v < VOCAB) {
#pragma unroll
        for (int j = 0; j < 16; ++j) {
            const int e_l = wv * 16 + j;
            tile[e_l][lane] = W_emb[(size_t)(e0c + e_l) * VOCAB + v];
        }
    }
    __syncthreads();

    for (int p = beg + wv; p < end; p += 4) {
        const int pk  = ws[WS_ENTS + p];
        const int ts  = pk & (NTOK - 1);
        const int v_l = pk >> 14;
        const int s   = ts & (SEQ - 1);
        const float val = tile[lane][v_l]
                        + W_pos[(size_t)s * EMB + e0c + lane];
        __builtin_nontemporal_store(val, &out[(size_t)ts * EMB + e0c + lane]);
    }
}

// Fallback: direct strided gather (correct anywhere, slow).
__global__ __launch_bounds__(256)
void gather_direct_k(const int* __restrict__ tokens,
                     const float* __restrict__ W_emb,
                     const floatx4* __restrict__ Wpos,
                     floatx4* __restrict__ out) {
    const int idx = blockIdx.x * blockDim.x + threadIdx.x;
    const int e4  = idx & (EMB / 4 - 1);
    const int ts  = idx >> 7;
    const int s   = ts & (SEQ - 1);
    const int t   = tokens[ts];
    const size_t base = (size_t)(4 * e4) * VOCAB + (size_t)t;
    floatx4 r;
    r.x = W_emb[base];
    r.y = W_emb[base + (size_t)VOCAB];
    r.z = W_emb[base + (size_t)(2 * VOCAB)];
    r.w = W_emb[base + (size_t)(3 * VOCAB)];
    __builtin_nontemporal_store(r + Wpos[(size_t)s * (EMB / 4) + e4], &out[idx]);
}

extern "C" void kernel_launch(void* const* d_in, const int* in_sizes, int n_in,
                              void* d_out, int out_size, void* d_ws, size_t ws_size,
                              hipStream_t stream) {
    const int*   tokens = (const int*)d_in[0];
    const float* W_emb  = (const float*)d_in[1];   // (EMB, VOCAB)
    const float* W_pos  = (const float*)d_in[2];   // (SEQ, EMB)
    float*       out    = (float*)d_out;           // (BATCH*SEQ, EMB)

    if (ws_size >= WS_NEED_BYTES) {
        int* ws = (int*)d_ws;
        init_k <<<4, 256, 0, stream>>>(ws);
        count_k<<<NTOK / 256, 256, 0, stream>>>(tokens, ws);
        scan_k <<<1, 256, 0, stream>>>(ws);
        fill_k <<<NTOK / 256, 256, 0, stream>>>(tokens, ws);
        fused_emb_k<<<dim3(NBINS, EMB / 64), 256, 0, stream>>>(W_emb, W_pos, ws, out);
    } else {
        const int gblocks = (NTOK * (EMB / 4)) / 256;
        gather_direct_k<<<gblocks, 256, 0, stream>>>(tokens, W_emb,
                                                     (const floatx4*)W_pos,
                                                     (floatx4*)out);
    }
}